// Round 9
// baseline (560.227 us; speedup 1.0000x reference)
//
#include <hip/hip_runtime.h>

#define FEATN 128
#define F3 384
#define NRBF 20
#define KPAD 32
#define EB 32
#define D0 0.1f
#define CUT 5.0f
#define PI_F 3.14159265358979323846f

typedef __attribute__((ext_vector_type(8))) short short8;
typedef __attribute__((ext_vector_type(4))) float f32x4;
typedef __attribute__((ext_vector_type(4))) unsigned int u32x4;

__device__ __forceinline__ unsigned short f2bf(float f) {
  unsigned int u = __float_as_uint(f);
  u += 0x7FFFu + ((u >> 16) & 1u);   // round-to-nearest-even
  return (unsigned short)(u >> 16);
}
__device__ __forceinline__ float bflo(unsigned int u) { return __uint_as_float(u << 16); }
__device__ __forceinline__ float bfhi(unsigned int u) { return __uint_as_float(u & 0xffff0000u); }

// XOR swizzle for [R][128]-bf16 LDS tiles: spreads 16B slots across banks (G4)
__device__ __forceinline__ int swz(int row, int col) {
  return row * 128 + (col ^ ((row & 7) << 3));
}

// ---------------------------------------------------------------------------
// Kernel 1: one-off weight prep (W1t/W2t/Wdt transposed bf16)
// ---------------------------------------------------------------------------
__global__ __launch_bounds__(256) void prep_kernel(const float* __restrict__ W1,
                                                   const float* __restrict__ W2,
                                                   const float* __restrict__ Wd,
                                                   unsigned short* __restrict__ W1t,
                                                   unsigned short* __restrict__ W2t,
                                                   unsigned short* __restrict__ Wdt) {
  const int idx = blockIdx.x * 256 + threadIdx.x;
  if (idx < FEATN * FEATN) {
    const int nn = idx >> 7, k = idx & 127;
    W1t[idx] = f2bf(W1[k * FEATN + nn]);
  }
  const int idx2 = idx - FEATN * FEATN;
  if (idx2 >= 0 && idx2 < F3 * FEATN) {
    const int nn = idx2 >> 7, k = idx2 & 127;
    W2t[idx2] = f2bf(W2[k * F3 + nn]);
  }
  const int idx3 = idx - FEATN * FEATN - F3 * FEATN;
  if (idx3 >= 0 && idx3 < F3 * KPAD) {
    const int c = idx3 >> 5, k = idx3 & 31;
    Wdt[idx3] = (k < NRBF) ? f2bf(Wd[k * F3 + c]) : (unsigned short)0;
  }
}

// ---------------------------------------------------------------------------
// Kernel 2: fused node transform via bf16 MFMA:
//   h = silu(s @ W1 + b1) @ W2 + b2   (h stored as bf16)
// ---------------------------------------------------------------------------
__global__ __launch_bounds__(256, 2) void node_mfma_kernel(
    const float* __restrict__ s, const unsigned short* __restrict__ W1t,
    const float* __restrict__ b1, const unsigned short* __restrict__ W2t,
    const float* __restrict__ b2, unsigned short* __restrict__ hbf, int n) {
  __shared__ unsigned short sA[64 * 128];   // 16 KB, swizzled
  __shared__ unsigned short sT[64 * 128];   // 16 KB, swizzled
  __shared__ unsigned short sW[128 * 128];  // 32 KB, swizzled (W1t, then W2t chunks)

  const int tid = threadIdx.x;
  const int w = tid >> 6;
  const int lane = tid & 63;
  const int row0 = blockIdx.x * 64;

#pragma unroll
  for (int i = 0; i < 8; ++i) {
    const int f = i * 256 + tid;
    const int r = f >> 5;
    const int c4 = f & 31;
    float4 v = make_float4(0.f, 0.f, 0.f, 0.f);
    if (row0 + r < n) v = *(const float4*)&s[(size_t)(row0 + r) * FEATN + c4 * 4];
    uint2 pk;
    pk.x = (unsigned)f2bf(v.x) | ((unsigned)f2bf(v.y) << 16);
    pk.y = (unsigned)f2bf(v.z) | ((unsigned)f2bf(v.w) << 16);
    *(uint2*)&sA[swz(r, c4 * 4)] = pk;
  }
#pragma unroll
  for (int i = 0; i < 8; ++i) {
    const int f = i * 256 + tid;
    const int r = f >> 4;
    const int c8 = f & 15;
    const uint4 v = *(const uint4*)&W1t[r * 128 + c8 * 8];
    *(uint4*)&sW[swz(r, c8 * 8)] = v;
  }
  __syncthreads();

  const int arow = w * 16 + (lane & 15);
  const int kbase = (lane >> 4) * 8;
  const int drow0 = w * 16 + ((lane >> 4) << 2);
  const int dcol = lane & 15;

  // ---- GEMM1: t = silu(s @ W1 + b1)
  {
    f32x4 acc[8] = {};
#pragma unroll
    for (int ks = 0; ks < 4; ++ks) {
      const int kk = ks * 32 + kbase;
      const short8 a = *(const short8*)&sA[swz(arow, kk)];
#pragma unroll
      for (int nf = 0; nf < 8; ++nf) {
        const short8 b = *(const short8*)&sW[swz(nf * 16 + dcol, kk)];
        acc[nf] = __builtin_amdgcn_mfma_f32_16x16x32_bf16(a, b, acc[nf], 0, 0, 0);
      }
    }
#pragma unroll
    for (int nf = 0; nf < 8; ++nf) {
      const int col = nf * 16 + dcol;
      const float bias = b1[col];
#pragma unroll
      for (int r = 0; r < 4; ++r) {
        const float v = acc[nf][r] + bias;
        const float t = v / (1.0f + __expf(-v));  // silu
        sT[swz(drow0 + r, col)] = f2bf(t);
      }
    }
  }
  __syncthreads();

  // ---- GEMM2: h = t @ W2 + b2, in 3 chunks of 128 cols
  for (int c = 0; c < 3; ++c) {
#pragma unroll
    for (int i = 0; i < 8; ++i) {
      const int f = i * 256 + tid;
      const int r = f >> 4;
      const int c8 = f & 15;
      const uint4 v = *(const uint4*)&W2t[(size_t)(c * 128 + r) * 128 + c8 * 8];
      *(uint4*)&sW[swz(r, c8 * 8)] = v;
    }
    __syncthreads();

    f32x4 acc2[8] = {};
#pragma unroll
    for (int ks = 0; ks < 4; ++ks) {
      const int kk = ks * 32 + kbase;
      const short8 a = *(const short8*)&sT[swz(arow, kk)];
#pragma unroll
      for (int nf = 0; nf < 8; ++nf) {
        const short8 b = *(const short8*)&sW[swz(nf * 16 + dcol, kk)];
        acc2[nf] = __builtin_amdgcn_mfma_f32_16x16x32_bf16(a, b, acc2[nf], 0, 0, 0);
      }
    }
#pragma unroll
    for (int nf = 0; nf < 8; ++nf) {
      const int col = c * 128 + nf * 16 + dcol;
      const float bias = b2[col];
#pragma unroll
      for (int r = 0; r < 4; ++r) {
        const int row = row0 + drow0 + r;
        if (row < n) hbf[(size_t)row * F3 + col] = f2bf(acc2[nf][r] + bias);
      }
    }
    __syncthreads();
  }
}

// ---------------------------------------------------------------------------
// Kernel 3: fused edge kernel, ORIGINAL edge order (R7/R8 lesson: sequential
// writes beat gather locality by a wide margin).
// Phase 1: threads 0..31 compute env-scaled rbf -> sA.
// Early-issue (T14): ALL threads issue their 6 h-row 16B loads into regs
// right after the phase-1 barrier; the phase-1b MFMA + LDS writes hide the
// ~400-600cy L3 gather latency.
// Phase 1b: w_s = (env*rbf) @ Wd + env*bd via MFMA -> sWS.
// Phase 2: pure LDS-read x reg x nt-store stream (no global-read dependency).
// ---------------------------------------------------------------------------
__global__ __launch_bounds__(256, 4) void edge_kernel(
    const float* __restrict__ dist, const int* __restrict__ nbrs,
    const unsigned short* __restrict__ hbf, const unsigned short* __restrict__ Wdt,
    const float* __restrict__ bd, float* __restrict__ out, int n_edges) {
  __shared__ unsigned short sA[EB * KPAD];   // 2 KB
  __shared__ unsigned short sWS[EB * F3];    // 24 KB
  __shared__ float env_ls[EB];
  __shared__ int nbr_ls[EB];

  const int tid = threadIdx.x;
  const int e0 = blockIdx.x * EB;

  // ---- Phase 1: per-edge scalars + rbf rows (threads 0..31)
  if (tid < EB) {
    const int e = e0 + tid;
    float d = 1.0f;
    int nbr = 0;
    float sc = 0.f, cc = 1.f, env = 0.f;
    if (e < n_edges) {
      d = dist[e];
      nbr = nbrs[2 * e + 1];
      const float th = (PI_F / CUT) * d;
      __sincosf(th, &sc, &cc);
      env = (d < CUT) ? 0.5f * (cc + 1.0f) : 0.0f;
    }
    nbr_ls[tid] = nbr;
    env_ls[tid] = env;
    const float einv = env / d;
    const float twoc = 2.0f * cc;
    float skm1 = 0.f, sk = sc;
    unsigned short* arow = &sA[tid * KPAD];
#pragma unroll
    for (int k = 0; k < NRBF; ++k) {
      arow[k] = f2bf(sk * einv);
      const float nxt = twoc * sk - skm1;
      skm1 = sk;
      sk = nxt;
    }
#pragma unroll
    for (int k = NRBF; k < KPAD; ++k) arow[k] = 0;
  }
  __syncthreads();

  // ---- Early-issue h gather into registers (unconditional: nbr defaults 0)
  u32x4 hr[6];
#pragma unroll
  for (int i = 0; i < 6; ++i) {
    const int qi = i * 256 + tid;
    const int le = qi / 48;
    const int sub = qi - le * 48;
    const int nbr = nbr_ls[le];
    hr[i] = *(const u32x4*)&hbf[(size_t)nbr * F3 + sub * 8];
  }

  // ---- Phase 1b: w_s via MFMA (overlaps the in-flight gather).
  {
    const int wv = tid >> 6, lane = tid & 63;
    const int rt = wv & 1, ch = wv >> 1;
    const short8 a = *(const short8*)&sA[(rt * 16 + (lane & 15)) * KPAD + (lane >> 4) * 8];
    const int bl = lane & 15;
    const int kb = (lane >> 4) * 8;
    const int rbase = rt * 16 + ((lane >> 4) << 2);
    float envr[4];
#pragma unroll
    for (int r = 0; r < 4; ++r) envr[r] = env_ls[rbase + r];

#pragma unroll
    for (int ct = 0; ct < 12; ++ct) {
      const int col = ch * 192 + ct * 16 + bl;
      const short8 b = *(const short8*)&Wdt[col * KPAD + kb];
      f32x4 acc = {};
      acc = __builtin_amdgcn_mfma_f32_16x16x32_bf16(a, b, acc, 0, 0, 0);
      const float bdv = bd[col];
#pragma unroll
      for (int r = 0; r < 4; ++r)
        sWS[(rbase + r) * F3 + col] = f2bf(acc[r] + envr[r] * bdv);
    }
  }
  __syncthreads();

  // ---- Phase 2: multiply preloaded h by w_s, stream out (32B/thread-iter)
#pragma unroll
  for (int i = 0; i < 6; ++i) {
    const int qi = i * 256 + tid;
    const int le = qi / 48;
    const int sub = qi - le * 48;
    if (e0 + le < n_edges) {
      const u32x4 hp = hr[i];
      const u32x4 wsv = *(const u32x4*)&sWS[le * F3 + sub * 8];
      f32x4 o0, o1;
      o0.x = bflo(hp.x) * bflo(wsv.x);
      o0.y = bfhi(hp.x) * bfhi(wsv.x);
      o0.z = bflo(hp.y) * bflo(wsv.y);
      o0.w = bfhi(hp.y) * bfhi(wsv.y);
      o1.x = bflo(hp.z) * bflo(wsv.z);
      o1.y = bfhi(hp.z) * bfhi(wsv.z);
      o1.z = bflo(hp.w) * bflo(wsv.w);
      o1.w = bfhi(hp.w) * bfhi(wsv.w);
      f32x4* op = (f32x4*)out + (size_t)e0 * 96 + le * 96 + sub * 2;
      __builtin_nontemporal_store(o0, op);
      __builtin_nontemporal_store(o1, op + 1);
    }
  }
}

// ---------------------------------------------------------------------------
extern "C" void kernel_launch(void* const* d_in, const int* in_sizes, int n_in,
                              void* d_out, int out_size, void* d_ws, size_t ws_size,
                              hipStream_t stream) {
  const float* s_j  = (const float*)d_in[0];
  const float* dist = (const float*)d_in[1];
  const int*   nbrs = (const int*)d_in[2];
  const float* W1   = (const float*)d_in[3];
  const float* b1   = (const float*)d_in[4];
  const float* W2   = (const float*)d_in[5];
  const float* b2   = (const float*)d_in[6];
  const float* Wd   = (const float*)d_in[7];
  const float* bd   = (const float*)d_in[8];
  float* out = (float*)d_out;

  const int n_nodes = in_sizes[0] / FEATN;
  const int n_edges = in_sizes[1];

  char* ws = (char*)d_ws;
  unsigned short* hbf = (unsigned short*)ws;                 // n_nodes*384*2 B
  unsigned short* W1t = hbf + (size_t)n_nodes * F3;
  unsigned short* W2t = W1t + FEATN * FEATN;
  unsigned short* Wdt = W2t + F3 * FEATN;

  const int prep_elems = FEATN * FEATN + F3 * FEATN + F3 * KPAD;
  hipLaunchKernelGGL(prep_kernel, dim3((prep_elems + 255) / 256), dim3(256), 0, stream,
                     W1, W2, Wd, W1t, W2t, Wdt);
  hipLaunchKernelGGL(node_mfma_kernel, dim3((n_nodes + 63) / 64), dim3(256), 0, stream,
                     s_j, W1t, b1, W2t, b2, hbf, n_nodes);
  hipLaunchKernelGGL(edge_kernel, dim3((n_edges + EB - 1) / EB), dim3(256), 0, stream,
                     dist, nbrs, hbf, Wdt, bd, out, n_edges);
}

// Round 10
// 315.508 us; speedup vs baseline: 1.7756x; 1.7756x over previous
//
#include <hip/hip_runtime.h>

#define FEATN 128
#define F3 384
#define NRBF 20
#define KPAD 32
#define EB 32
#define D0 0.1f
#define CUT 5.0f
#define PI_F 3.14159265358979323846f

typedef __attribute__((ext_vector_type(8))) short short8;
typedef __attribute__((ext_vector_type(4))) float f32x4;

__device__ __forceinline__ unsigned short f2bf(float f) {
  unsigned int u = __float_as_uint(f);
  u += 0x7FFFu + ((u >> 16) & 1u);   // round-to-nearest-even
  return (unsigned short)(u >> 16);
}
__device__ __forceinline__ float bflo(unsigned int u) { return __uint_as_float(u << 16); }
__device__ __forceinline__ float bfhi(unsigned int u) { return __uint_as_float(u & 0xffff0000u); }

// XOR swizzle for [R][128]-bf16 LDS tiles: spreads 16B slots across banks (G4)
__device__ __forceinline__ int swz(int row, int col) {
  return row * 128 + (col ^ ((row & 7) << 3));
}

// ---------------------------------------------------------------------------
// Kernel 1: one-off weight prep (W1t/W2t/Wdt transposed bf16)
// ---------------------------------------------------------------------------
__global__ __launch_bounds__(256) void prep_kernel(const float* __restrict__ W1,
                                                   const float* __restrict__ W2,
                                                   const float* __restrict__ Wd,
                                                   unsigned short* __restrict__ W1t,
                                                   unsigned short* __restrict__ W2t,
                                                   unsigned short* __restrict__ Wdt) {
  const int idx = blockIdx.x * 256 + threadIdx.x;
  if (idx < FEATN * FEATN) {
    const int nn = idx >> 7, k = idx & 127;
    W1t[idx] = f2bf(W1[k * FEATN + nn]);
  }
  const int idx2 = idx - FEATN * FEATN;
  if (idx2 >= 0 && idx2 < F3 * FEATN) {
    const int nn = idx2 >> 7, k = idx2 & 127;
    W2t[idx2] = f2bf(W2[k * F3 + nn]);
  }
  const int idx3 = idx - FEATN * FEATN - F3 * FEATN;
  if (idx3 >= 0 && idx3 < F3 * KPAD) {
    const int c = idx3 >> 5, k = idx3 & 31;
    Wdt[idx3] = (k < NRBF) ? f2bf(Wd[k * F3 + c]) : (unsigned short)0;
  }
}

// ---------------------------------------------------------------------------
// Kernel 2: fused node transform via bf16 MFMA:
//   h = silu(s @ W1 + b1) @ W2 + b2   (h stored as bf16)
// ---------------------------------------------------------------------------
__global__ __launch_bounds__(256, 2) void node_mfma_kernel(
    const float* __restrict__ s, const unsigned short* __restrict__ W1t,
    const float* __restrict__ b1, const unsigned short* __restrict__ W2t,
    const float* __restrict__ b2, unsigned short* __restrict__ hbf, int n) {
  __shared__ unsigned short sA[64 * 128];   // 16 KB, swizzled
  __shared__ unsigned short sT[64 * 128];   // 16 KB, swizzled
  __shared__ unsigned short sW[128 * 128];  // 32 KB, swizzled (W1t, then W2t chunks)

  const int tid = threadIdx.x;
  const int w = tid >> 6;
  const int lane = tid & 63;
  const int row0 = blockIdx.x * 64;

#pragma unroll
  for (int i = 0; i < 8; ++i) {
    const int f = i * 256 + tid;
    const int r = f >> 5;
    const int c4 = f & 31;
    float4 v = make_float4(0.f, 0.f, 0.f, 0.f);
    if (row0 + r < n) v = *(const float4*)&s[(size_t)(row0 + r) * FEATN + c4 * 4];
    uint2 pk;
    pk.x = (unsigned)f2bf(v.x) | ((unsigned)f2bf(v.y) << 16);
    pk.y = (unsigned)f2bf(v.z) | ((unsigned)f2bf(v.w) << 16);
    *(uint2*)&sA[swz(r, c4 * 4)] = pk;
  }
#pragma unroll
  for (int i = 0; i < 8; ++i) {
    const int f = i * 256 + tid;
    const int r = f >> 4;
    const int c8 = f & 15;
    const uint4 v = *(const uint4*)&W1t[r * 128 + c8 * 8];
    *(uint4*)&sW[swz(r, c8 * 8)] = v;
  }
  __syncthreads();

  const int arow = w * 16 + (lane & 15);
  const int kbase = (lane >> 4) * 8;
  const int drow0 = w * 16 + ((lane >> 4) << 2);
  const int dcol = lane & 15;

  // ---- GEMM1: t = silu(s @ W1 + b1)
  {
    f32x4 acc[8] = {};
#pragma unroll
    for (int ks = 0; ks < 4; ++ks) {
      const int kk = ks * 32 + kbase;
      const short8 a = *(const short8*)&sA[swz(arow, kk)];
#pragma unroll
      for (int nf = 0; nf < 8; ++nf) {
        const short8 b = *(const short8*)&sW[swz(nf * 16 + dcol, kk)];
        acc[nf] = __builtin_amdgcn_mfma_f32_16x16x32_bf16(a, b, acc[nf], 0, 0, 0);
      }
    }
#pragma unroll
    for (int nf = 0; nf < 8; ++nf) {
      const int col = nf * 16 + dcol;
      const float bias = b1[col];
#pragma unroll
      for (int r = 0; r < 4; ++r) {
        const float v = acc[nf][r] + bias;
        const float t = v / (1.0f + __expf(-v));  // silu
        sT[swz(drow0 + r, col)] = f2bf(t);
      }
    }
  }
  __syncthreads();

  // ---- GEMM2: h = t @ W2 + b2, in 3 chunks of 128 cols
  for (int c = 0; c < 3; ++c) {
#pragma unroll
    for (int i = 0; i < 8; ++i) {
      const int f = i * 256 + tid;
      const int r = f >> 4;
      const int c8 = f & 15;
      const uint4 v = *(const uint4*)&W2t[(size_t)(c * 128 + r) * 128 + c8 * 8];
      *(uint4*)&sW[swz(r, c8 * 8)] = v;
    }
    __syncthreads();

    f32x4 acc2[8] = {};
#pragma unroll
    for (int ks = 0; ks < 4; ++ks) {
      const int kk = ks * 32 + kbase;
      const short8 a = *(const short8*)&sT[swz(arow, kk)];
#pragma unroll
      for (int nf = 0; nf < 8; ++nf) {
        const short8 b = *(const short8*)&sW[swz(nf * 16 + dcol, kk)];
        acc2[nf] = __builtin_amdgcn_mfma_f32_16x16x32_bf16(a, b, acc2[nf], 0, 0, 0);
      }
    }
#pragma unroll
    for (int nf = 0; nf < 8; ++nf) {
      const int col = c * 128 + nf * 16 + dcol;
      const float bias = b2[col];
#pragma unroll
      for (int r = 0; r < 4; ++r) {
        const int row = row0 + drow0 + r;
        if (row < n) hbf[(size_t)row * F3 + col] = f2bf(acc2[nf][r] + bias);
      }
    }
    __syncthreads();
  }
}

// ---------------------------------------------------------------------------
// Kernel 3: fused edge kernel, ORIGINAL edge order (R7/R8: sequential writes
// beat gather locality). R6 structure; phase 2 now DENSE-store layout:
// thread -> one output quad qo, consecutive lanes -> consecutive 16B, so each
// wave nt-store instruction is a dense 1KB burst (R6 was 32B-strided 16B
// stores, holey bursts to the nt write path).
// ---------------------------------------------------------------------------
__global__ __launch_bounds__(256, 4) void edge_kernel(
    const float* __restrict__ dist, const int* __restrict__ nbrs,
    const unsigned short* __restrict__ hbf, const unsigned short* __restrict__ Wdt,
    const float* __restrict__ bd, float* __restrict__ out, int n_edges) {
  __shared__ unsigned short sA[EB * KPAD];   // 2 KB
  __shared__ unsigned short sWS[EB * F3];    // 24 KB
  __shared__ float env_ls[EB];
  __shared__ int nbr_ls[EB];

  const int tid = threadIdx.x;
  const int e0 = blockIdx.x * EB;

  // ---- Phase 1: per-edge scalars + rbf rows (threads 0..31)
  if (tid < EB) {
    const int e = e0 + tid;
    float d = 1.0f;
    int nbr = 0;
    float sc = 0.f, cc = 1.f, env = 0.f;
    if (e < n_edges) {
      d = dist[e];
      nbr = nbrs[2 * e + 1];
      const float th = (PI_F / CUT) * d;
      __sincosf(th, &sc, &cc);
      env = (d < CUT) ? 0.5f * (cc + 1.0f) : 0.0f;
    }
    nbr_ls[tid] = nbr;
    env_ls[tid] = env;
    const float einv = env / d;
    const float twoc = 2.0f * cc;
    float skm1 = 0.f, sk = sc;
    unsigned short* arow = &sA[tid * KPAD];
#pragma unroll
    for (int k = 0; k < NRBF; ++k) {
      arow[k] = f2bf(sk * einv);
      const float nxt = twoc * sk - skm1;
      skm1 = sk;
      sk = nxt;
    }
#pragma unroll
    for (int k = NRBF; k < KPAD; ++k) arow[k] = 0;
  }
  __syncthreads();

  // ---- Phase 1b: w_s via MFMA. wave wv: row-tile rt=wv&1, col-half ch=wv>>1.
  {
    const int wv = tid >> 6, lane = tid & 63;
    const int rt = wv & 1, ch = wv >> 1;
    const short8 a = *(const short8*)&sA[(rt * 16 + (lane & 15)) * KPAD + (lane >> 4) * 8];
    const int bl = lane & 15;
    const int kb = (lane >> 4) * 8;
    const int rbase = rt * 16 + ((lane >> 4) << 2);
    float envr[4];
#pragma unroll
    for (int r = 0; r < 4; ++r) envr[r] = env_ls[rbase + r];

#pragma unroll
    for (int ct = 0; ct < 12; ++ct) {
      const int col = ch * 192 + ct * 16 + bl;
      const short8 b = *(const short8*)&Wdt[col * KPAD + kb];
      f32x4 acc = {};
      acc = __builtin_amdgcn_mfma_f32_16x16x32_bf16(a, b, acc, 0, 0, 0);
      const float bdv = bd[col];
#pragma unroll
      for (int r = 0; r < 4; ++r)
        sWS[(rbase + r) * F3 + col] = f2bf(acc[r] + envr[r] * bdv);
    }
  }
  __syncthreads();

  // ---- Phase 2: dense-store stream. qo = output quad index in block.
  // Per thread-iter: 8B h load + 8B LDS read + one dense 16B nt store.
#pragma unroll
  for (int i = 0; i < (EB * 96) / 256; ++i) {   // 12 iterations
    const int qo = i * 256 + tid;
    const int le = qo / 96;
    const int q = qo - le * 96;
    if (e0 + le < n_edges) {
      const int nbr = nbr_ls[le];
      const uint2 hp = *(const uint2*)&hbf[(size_t)nbr * F3 + q * 4];
      const uint2 wsv = *(const uint2*)&sWS[le * F3 + q * 4];
      f32x4 o;
      o.x = bflo(hp.x) * bflo(wsv.x);
      o.y = bfhi(hp.x) * bfhi(wsv.x);
      o.z = bflo(hp.y) * bflo(wsv.y);
      o.w = bfhi(hp.y) * bfhi(wsv.y);
      __builtin_nontemporal_store(o, (f32x4*)out + (size_t)e0 * 96 + qo);
    }
  }
}

// ---------------------------------------------------------------------------
extern "C" void kernel_launch(void* const* d_in, const int* in_sizes, int n_in,
                              void* d_out, int out_size, void* d_ws, size_t ws_size,
                              hipStream_t stream) {
  const float* s_j  = (const float*)d_in[0];
  const float* dist = (const float*)d_in[1];
  const int*   nbrs = (const int*)d_in[2];
  const float* W1   = (const float*)d_in[3];
  const float* b1   = (const float*)d_in[4];
  const float* W2   = (const float*)d_in[5];
  const float* b2   = (const float*)d_in[6];
  const float* Wd   = (const float*)d_in[7];
  const float* bd   = (const float*)d_in[8];
  float* out = (float*)d_out;

  const int n_nodes = in_sizes[0] / FEATN;
  const int n_edges = in_sizes[1];

  char* ws = (char*)d_ws;
  unsigned short* hbf = (unsigned short*)ws;                 // n_nodes*384*2 B
  unsigned short* W1t = hbf + (size_t)n_nodes * F3;
  unsigned short* W2t = W1t + FEATN * FEATN;
  unsigned short* Wdt = W2t + F3 * FEATN;

  const int prep_elems = FEATN * FEATN + F3 * FEATN + F3 * KPAD;
  hipLaunchKernelGGL(prep_kernel, dim3((prep_elems + 255) / 256), dim3(256), 0, stream,
                     W1, W2, Wd, W1t, W2t, Wdt);
  hipLaunchKernelGGL(node_mfma_kernel, dim3((n_nodes + 63) / 64), dim3(256), 0, stream,
                     s_j, W1t, b1, W2t, b2, hbf, n_nodes);
  hipLaunchKernelGGL(edge_kernel, dim3((n_edges + EB - 1) / EB), dim3(256), 0, stream,
                     dist, nbrs, hbf, Wdt, bd, out, n_edges);
}